// Round 11
// baseline (220.759 us; speedup 1.0000x reference)
//
#include <hip/hip_runtime.h>
#include <hip/hip_bf16.h>
#include <stdint.h>

typedef __bf16 bf16x8 __attribute__((ext_vector_type(8)));
typedef float f32x4 __attribute__((ext_vector_type(4)));

#define T_SEQ 4096
#define C_DIM 1024
#define H_NUM 16
#define HD 64
#define C3 3072
#define NEG_BIG (-30000.0f)

__device__ __forceinline__ unsigned short f2bf(float f) {
    uint32_t u = __builtin_bit_cast(uint32_t, f);
    u += 0x7fffu + ((u >> 16) & 1u);
    return (unsigned short)(u >> 16);
}

__device__ __forceinline__ uint32_t pk_bf16(float a, float b) {
    __hip_bfloat162 h = __float22bfloat162_rn(float2{a, b});
    uint32_t u;
    __builtin_memcpy(&u, &h, sizeof(u));
    return u;
}

__device__ __forceinline__ bf16x8 ld_bf8(const unsigned short* p) {
    return *reinterpret_cast<const bf16x8*>(p);
}

__device__ __forceinline__ void async_g2l16(const unsigned short* g, unsigned short* l) {
    __builtin_amdgcn_global_load_lds(
        (const __attribute__((address_space(1))) void*)g,
        (__attribute__((address_space(3))) void*)l, 16, 0, 0);
}

__device__ __forceinline__ void store_c(unsigned short* C, size_t idx, float v) { C[idx] = f2bf(v); }
__device__ __forceinline__ void store_c(float* C, size_t idx, float v)          { C[idx] = v; }

__device__ __forceinline__ void cvt8(const float* src, unsigned short* dst) {
    float4 f0 = *(const float4*)src;
    float4 f1 = *(const float4*)(src + 4);
    union { uint32_t w[4]; uint4 q; } t;
    t.w[0] = pk_bf16(f0.x, f0.y);
    t.w[1] = pk_bf16(f0.z, f0.w);
    t.w[2] = pk_bf16(f1.x, f1.y);
    t.w[3] = pk_bf16(f1.z, f1.w);
    *(uint4*)dst = t.q;
}

// x and w_attn fp32 -> bf16 in one launch (concatenated index space)
__global__ void cvt_xw(const float* __restrict__ x, const float* __restrict__ wa,
                       unsigned short* __restrict__ xb, unsigned short* __restrict__ wab) {
    int i = (blockIdx.x * blockDim.x + threadIdx.x) * 8;
    if (i < T_SEQ * C_DIM) cvt8(x + i, xb + i);
    else {
        int k = i - T_SEQ * C_DIM;
        if (k < C3 * C_DIM) cvt8(wa + k, wab + k);
    }
}

__global__ void cvt_f32_bf16(const float* __restrict__ src, unsigned short* __restrict__ dst, int n) {
    int i = (blockIdx.x * blockDim.x + threadIdx.x) * 8;
    if (i >= n) return;
    cvt8(src + i, dst + i);
}

// V part of qkv [T][3C] -> Vt [C][T], 64x64 tiles through padded LDS.
__global__ __launch_bounds__(256) void v_transpose(
    const unsigned short* __restrict__ qkv, unsigned short* __restrict__ Vt)
{
    __shared__ unsigned short tile[64][72];
    const int t0 = blockIdx.x * 64, c0 = blockIdx.y * 64;
    const int r = threadIdx.x >> 2, q = threadIdx.x & 3;

    const unsigned short* src = qkv + (size_t)(t0 + r) * C3 + 2 * C_DIM + c0 + q * 16;
    *(uint4*)&tile[r][q * 16]     = *(const uint4*)src;
    *(uint4*)&tile[r][q * 16 + 8] = *(const uint4*)(src + 8);
    __syncthreads();

    union { unsigned short u[16]; uint4 v[2]; } o;
    #pragma unroll
    for (int j = 0; j < 16; ++j) o.u[j] = tile[q * 16 + j][r];
    unsigned short* dst = Vt + (size_t)(c0 + r) * T_SEQ + t0 + q * 16;
    *(uint4*)dst       = o.v[0];
    *(uint4*)(dst + 8) = o.v[1];
}

// C = A @ B^T, bf16, m97 async staging. 128x128 tile, BK=32.
template <typename TC>
__global__ __launch_bounds__(256, 2) void gemm_bt(
    const unsigned short* __restrict__ A, const unsigned short* __restrict__ B,
    TC* __restrict__ C, int M, int N, int K)
{
    __shared__ __attribute__((aligned(16))) unsigned short As[128 * 32];
    __shared__ __attribute__((aligned(16))) unsigned short Bs[128 * 32];

    const int tid  = threadIdx.x;
    const int wave = tid >> 6, lane = tid & 63;
    const int quad = lane >> 4, l16 = lane & 15;
    const int wm = wave >> 1, wn = wave & 1;
    const int m0 = blockIdx.y * 128, n0 = blockIdx.x * 128;

    const int srow = wave * 32 + (lane >> 2);
    const int scol = (lane & 3) * 8;

    f32x4 acc[4][4] = {};

    for (int k0 = 0; k0 < K; k0 += 32) {
        {
            const unsigned short* ga = A + (size_t)(m0 + srow) * K + k0 + scol;
            const unsigned short* gb = B + (size_t)(n0 + srow) * K + k0 + scol;
            unsigned short* la = As + (wave * 32) * 32;
            unsigned short* lb = Bs + (wave * 32) * 32;
            async_g2l16(ga, la);
            async_g2l16(ga + (size_t)16 * K, la + 16 * 32);
            async_g2l16(gb, lb);
            async_g2l16(gb + (size_t)16 * K, lb + 16 * 32);
        }
        __syncthreads();

        bf16x8 af[4], bf[4];
        #pragma unroll
        for (int i = 0; i < 4; ++i) {
            af[i] = ld_bf8(As + (wm * 64 + i * 16 + l16) * 32 + quad * 8);
            bf[i] = ld_bf8(Bs + (wn * 64 + i * 16 + l16) * 32 + quad * 8);
        }
        #pragma unroll
        for (int mt = 0; mt < 4; ++mt)
            #pragma unroll
            for (int nt = 0; nt < 4; ++nt)
                acc[mt][nt] = __builtin_amdgcn_mfma_f32_16x16x32_bf16(
                    af[mt], bf[nt], acc[mt][nt], 0, 0, 0);
        __syncthreads();
    }

    #pragma unroll
    for (int mt = 0; mt < 4; ++mt)
        #pragma unroll
        for (int nt = 0; nt < 4; ++nt)
            #pragma unroll
            for (int r = 0; r < 4; ++r) {
                int row = m0 + wm * 64 + mt * 16 + quad * 4 + r;
                int col = n0 + wn * 64 + nt * 16 + l16;
                store_c(C, (size_t)row * N + col, acc[mt][nt][r]);
            }
}

// One flash tile, 32 q-rows/wave (2 q-subtiles), max-free softmax.
template <bool MASK>
__device__ __forceinline__ void fa8_tile(
    const unsigned short* Ksb, const unsigned short* Vsb, unsigned short* pbuf,
    const bf16x8 qf[2][2], f32x4 o[2][4], float* l_part,
    int k0, int q_abs0, int quad, int l16, int sw, int fo0, int fo1)
{
    const unsigned short* krow = Ksb + l16 * 64;
    bf16x8 kf[4][2];
    #pragma unroll
    for (int s = 0; s < 4; ++s) {
        kf[s][0] = ld_bf8(krow + s * 1024 + fo0);
        kf[s][1] = ld_bf8(krow + s * 1024 + fo1);
    }

    #pragma unroll
    for (int qs = 0; qs < 2; ++qs) {
        f32x4 st[4];
        #pragma unroll
        for (int s = 0; s < 4; ++s) {
            f32x4 z = {};
            z = __builtin_amdgcn_mfma_f32_16x16x32_bf16(kf[s][0], qf[qs][0], z, 0, 0, 0);
            st[s] = __builtin_amdgcn_mfma_f32_16x16x32_bf16(kf[s][1], qf[qs][1], z, 0, 0, 0);
        }
        float ts = 0.f;
        #pragma unroll
        for (int s = 0; s < 4; ++s)
            #pragma unroll
            for (int r = 0; r < 4; ++r) {
                float v = st[s][r];
                if (MASK) {
                    int key = k0 + s * 16 + quad * 4 + r;
                    v = (key <= q_abs0 + qs * 16) ? v : NEG_BIG;
                }
                float e = __builtin_amdgcn_exp2f(v);   // exp2(-30000) = 0
                st[s][r] = e;
                ts += e;
            }
        l_part[qs] += ts;

        unsigned short* prow = pbuf + (qs * 16 + l16) * 64;
        #pragma unroll
        for (int s = 0; s < 4; ++s) {
            int g = 2 * s + (quad >> 1);
            uint2 pk;
            pk.x = pk_bf16(st[s][0], st[s][1]);
            pk.y = pk_bf16(st[s][2], st[s][3]);
            *(uint2*)((char*)prow + (g ^ sw) * 16 + 8 * (quad & 1)) = pk;
        }
    }

    const unsigned short* vrow = Vsb + l16 * 64;
    bf16x8 vf[4][2];
    #pragma unroll
    for (int c = 0; c < 4; ++c) {
        vf[c][0] = ld_bf8(vrow + c * 1024 + fo0);
        vf[c][1] = ld_bf8(vrow + c * 1024 + fo1);
    }
    #pragma unroll
    for (int qs = 0; qs < 2; ++qs) {
        const unsigned short* prow = pbuf + (qs * 16 + l16) * 64;
        bf16x8 pf0 = ld_bf8(prow + fo0);
        bf16x8 pf1 = ld_bf8(prow + fo1);
        #pragma unroll
        for (int c = 0; c < 4; ++c) {
            o[qs][c] = __builtin_amdgcn_mfma_f32_16x16x32_bf16(vf[c][0], pf0, o[qs][c], 0, 0, 0);
            o[qs][c] = __builtin_amdgcn_mfma_f32_16x16x32_bf16(vf[c][1], pf1, o[qs][c], 0, 0, 0);
        }
    }
}

// Flash v8: 4-wave blocks, 128 q-rows (32/wave), 512 equal-work blocks,
// 48KB LDS -> 3 blocks/CU = 12 waves/CU, dbuf K/V staging, max-free softmax.
__global__ __launch_bounds__(256, 3) void flash_attn8(
    const unsigned short* __restrict__ qkv,
    const unsigned short* __restrict__ Vt,
    unsigned short* __restrict__ Y)
{
    __shared__ __attribute__((aligned(16))) unsigned short Ks[2][64 * 64];
    __shared__ __attribute__((aligned(16))) unsigned short Vs[2][64 * 64];
    __shared__ __attribute__((aligned(16))) unsigned short Pl[4][32 * 64];

    const int tid  = threadIdx.x;
    const int wave = tid >> 6, lane = tid & 63;
    const int quad = lane >> 4, l16 = lane & 15;

    // 512 blocks: slot (h, j) x 2 rounds; qb = {j, 31-j} -> 68 tiles/slot, equal.
    const int bi = blockIdx.x;
    const int rr = bi >> 8, ss = bi & 255;
    const int h  = ss & 15;
    const int j  = ss >> 4;
    const int qb = rr ? (31 - j) : j;          // [0,32), 128 q-rows each

    const int q0w    = qb * 128 + wave * 32;
    const int q_abs0 = q0w + l16;              // qs=0 row; qs=1 adds 16
    const int sw  = l16 & 7;
    const int fo0 = (quad ^ sw) * 8;
    const int fo1 = ((quad + 4) ^ sw) * 8;

    // Q fragments (B-operand), prescaled by 0.125*log2(e); 2 q-subtiles
    bf16x8 qf[2][2];
    {
        const float QS = 0.125f * 1.44269504f;
        #pragma unroll
        for (int qs = 0; qs < 2; ++qs) {
            const unsigned short* qp =
                qkv + (size_t)(q0w + qs * 16 + l16) * C3 + h * HD + quad * 8;
            bf16x8 a = ld_bf8(qp), b = ld_bf8(qp + 32);
            #pragma unroll
            for (int i = 0; i < 8; ++i) {
                qf[qs][0][i] = (__bf16)((float)a[i] * QS);
                qf[qs][1][i] = (__bf16)((float)b[i] * QS);
            }
        }
    }

    // staging: 64 K rows + 64 V rows per block; wave stages 16+16 rows (2+2 calls)
    const int srow = lane >> 3;
    const int schunk = (lane & 7) ^ srow;
    const unsigned short* kp0 =
        qkv + (size_t)(wave * 16 + srow) * C3 + C_DIM + h * HD + schunk * 8;
    const unsigned short* kp1 = kp0 + (size_t)8 * C3;
    const unsigned short* vp0 =
        Vt + (size_t)(h * HD + wave * 16 + srow) * T_SEQ + schunk * 8;
    const unsigned short* vp1 = vp0 + (size_t)8 * T_SEQ;
    unsigned short* lk0  = Ks[0] + (wave * 16) * 64;
    unsigned short* lk0b = lk0 + 8 * 64;
    unsigned short* lv0  = Vs[0] + (wave * 16) * 64;
    unsigned short* lv0b = lv0 + 8 * 64;
    const int lds_db = 64 * 64;

    f32x4 o[2][4] = {};
    float l_part[2] = {0.f, 0.f};
    unsigned short* pbuf = Pl[wave];

    const int ntiles = 2 * qb + 2;
    const int mask_t = 2 * qb + (wave >> 1);   // waves 0,1 end at 2qb; 2,3 at 2qb+1

    async_g2l16(kp0, lk0);  async_g2l16(kp1, lk0b);
    async_g2l16(vp0, lv0);  async_g2l16(vp1, lv0b);
    kp0 += (size_t)64 * C3; kp1 += (size_t)64 * C3;
    vp0 += 64;              vp1 += 64;

    for (int t = 0; t < ntiles; ++t) {
        __syncthreads();
        const int b = t & 1;
        if (t + 1 < ntiles) {
            const int nb = 1 - b;
            async_g2l16(kp0, lk0 + nb * lds_db);
            async_g2l16(kp1, lk0b + nb * lds_db);
            async_g2l16(vp0, lv0 + nb * lds_db);
            async_g2l16(vp1, lv0b + nb * lds_db);
            kp0 += (size_t)64 * C3; kp1 += (size_t)64 * C3;
            vp0 += 64;              vp1 += 64;
        }
        if (t < mask_t) {
            fa8_tile<false>(Ks[b], Vs[b], pbuf, qf, o, l_part,
                            t * 64, q_abs0, quad, l16, sw, fo0, fo1);
        } else if (t == mask_t) {
            fa8_tile<true>(Ks[b], Vs[b], pbuf, qf, o, l_part,
                           t * 64, q_abs0, quad, l16, sw, fo0, fo1);
        }
        // waves 0,1 idle (barrier only) on tile 2qb+1
    }

    #pragma unroll
    for (int qs = 0; qs < 2; ++qs) {
        float l = l_part[qs];
        l += __shfl_xor(l, 16, 64);
        l += __shfl_xor(l, 32, 64);
        float inv_l = 1.f / l;
        #pragma unroll
        for (int c = 0; c < 4; ++c) {
            union { uint32_t w[2]; uint2 q; } t;
            t.w[0] = pk_bf16(o[qs][c][0] * inv_l, o[qs][c][1] * inv_l);
            t.w[1] = pk_bf16(o[qs][c][2] * inv_l, o[qs][c][3] * inv_l);
            *(uint2*)(Y + (size_t)(q_abs0 + qs * 16) * C_DIM + h * HD + c * 16 + quad * 4) = t.q;
        }
    }
}

extern "C" void kernel_launch(void* const* d_in, const int* in_sizes, int n_in,
                              void* d_out, int out_size, void* d_ws, size_t ws_size,
                              hipStream_t stream) {
    const float* x      = (const float*)d_in[0];
    const float* w_attn = (const float*)d_in[1];
    const float* w_proj = (const float*)d_in[2];
    float* out = (float*)d_out;

    unsigned short* qkv = (unsigned short*)d_ws;            // [4096,3072] bf16
    unsigned short* xb  = qkv + (size_t)T_SEQ * C3;         // [4096,1024] bf16
    unsigned short* y   = xb;                               // alias after gemm1
    unsigned short* wpb = qkv;                              // alias after flash
    unsigned short* Vt  = (unsigned short*)d_out;           // [1024][4096] bf16
    unsigned short* wab = Vt + (size_t)C_DIM * T_SEQ;       // [3072,1024] bf16

    cvt_xw<<<(T_SEQ * C_DIM + C3 * C_DIM) / 8 / 256, 256, 0, stream>>>(x, w_attn, xb, wab);

    gemm_bt<unsigned short>
        <<<dim3(C3 / 128, T_SEQ / 128), 256, 0, stream>>>(xb, wab, qkv, T_SEQ, C3, C_DIM);

    v_transpose<<<dim3(T_SEQ / 64, C_DIM / 64), 256, 0, stream>>>(qkv, Vt);

    flash_attn8<<<dim3(512), 256, 0, stream>>>(qkv, Vt, y);

    cvt_f32_bf16<<<(C_DIM * C_DIM / 8 + 255) / 256, 256, 0, stream>>>(w_proj, wpb, C_DIM * C_DIM);
    gemm_bt<float>
        <<<dim3(C_DIM / 128, T_SEQ / 128), 256, 0, stream>>>(y, wpb, out, T_SEQ, C_DIM, C_DIM);
}